// Round 17
// baseline (345.656 us; speedup 1.0000x reference)
//
#include <hip/hip_runtime.h>

#define E_EDGES 640000
#define NN 10000
#define HID 32
#define EDIM 128
#define CH 50      // GRU steps per LDS chunk
#define CCH 50     // output steps per scan block
#define WARM 100   // warmup steps (multiple of CH)
#define NBLK 200   // NN / CCH

typedef _Float16 f16;
typedef _Float16 f16x8 __attribute__((ext_vector_type(8)));
typedef _Float16 f16x2 __attribute__((ext_vector_type(2)));
typedef float f32x4 __attribute__((ext_vector_type(4)));

static __device__ __forceinline__ f16x2 pkrtz(float a, float b) {
  auto t = __builtin_amdgcn_cvt_pkrtz(a, b);
  f16x2 r;
  __builtin_memcpy(&r, &t, 4);
  return r;
}

static __device__ __forceinline__ f16x8 cvt8(float4 a, float4 b) {
  auto p0 = __builtin_amdgcn_cvt_pkrtz(a.x, a.y);
  auto p1 = __builtin_amdgcn_cvt_pkrtz(a.z, a.w);
  auto p2 = __builtin_amdgcn_cvt_pkrtz(b.x, b.y);
  auto p3 = __builtin_amdgcn_cvt_pkrtz(b.z, b.w);
  f16x8 r;
  __builtin_memcpy((char*)&r,      &p0, 4);
  __builtin_memcpy((char*)&r + 4,  &p1, 4);
  __builtin_memcpy((char*)&r + 8,  &p2, 4);
  __builtin_memcpy((char*)&r + 12, &p3, 4);
  return r;
}

static __device__ __forceinline__ f16x8 cvt8v(f32x4 a, f32x4 b) {
  auto p0 = __builtin_amdgcn_cvt_pkrtz(a[0], a[1]);
  auto p1 = __builtin_amdgcn_cvt_pkrtz(a[2], a[3]);
  auto p2 = __builtin_amdgcn_cvt_pkrtz(b[0], b[1]);
  auto p3 = __builtin_amdgcn_cvt_pkrtz(b[2], b[3]);
  f16x8 r;
  __builtin_memcpy((char*)&r,      &p0, 4);
  __builtin_memcpy((char*)&r + 4,  &p1, 4);
  __builtin_memcpy((char*)&r + 8,  &p2, 4);
  __builtin_memcpy((char*)&r + 12, &p3, 4);
  return r;
}

static __device__ __forceinline__ f16x8 splat8(float h) {
  auto p = __builtin_amdgcn_cvt_pkrtz(h, h);
  int si;
  __builtin_memcpy(&si, &p, 4);
  int v[4] = {si, si, si, si};
  f16x8 r;
  __builtin_memcpy(&r, v, 16);
  return r;
}

// ---------------- prep: zero agg, build f16 fragment-ordered weights ----------------
__global__ __launch_bounds__(256) void prep_kernel(
    const float* __restrict__ w1, const float* __restrict__ w2,
    const float* __restrict__ b2, float* __restrict__ agg,
    f16* __restrict__ Wf, f16* __restrict__ W1f)
{
  int tid = blockIdx.x * 256 + threadIdx.x;
  if (tid < NN * HID) agg[tid] = 0.f;
  if (tid < 33 * 1024) {
    int r = tid & 7, l = (tid >> 3) & 63, h = (tid >> 9) & 1, c2 = tid >> 10;
    int i = (l & 15) + 16 * h, j = (l >> 4) * 8 + r;
    float v = (c2 < 32) ? w2[c2 * 1024 + i * 32 + j] : b2[i * 32 + j];
    Wf[tid] = (f16)v;
  }
  if (tid < 4 * 1024) {
    int r = tid & 7, l = (tid >> 3) & 63, h = (tid >> 9) & 1, c = tid >> 10;
    int d = c * 32 + (l >> 4) * 8 + r, k = (l & 15) + 16 * h;
    W1f[tid] = (f16)w1[d * 32 + k];
  }
}

// ---------------- gemm1: PURE STREAM  h1 = relu(ea@W1+b1), fragment-layout f16 out ----------------
// h1p byte layout: [e-tile of 64][tt:4][lane:64][8 f16] ; value order per lane:
//   w[r]   = h1[e0+tt*16+g4*4+r][m16]      (r=0..3)
//   w[4+r] = h1[e0+tt*16+g4*4+r][m16+16]
__global__ __launch_bounds__(256) void gemm1_kernel(
    const float* __restrict__ ea, const float* __restrict__ b1,
    const f16* __restrict__ W1f, char* __restrict__ h1p)
{
  int t = threadIdx.x;
  int wave = t >> 6, l = t & 63;
  long e0 = ((long)blockIdx.x * 4 + wave) * 64;
  int m16 = l & 15, g4 = l >> 4;

  f32x4 acc[4][2];
  #pragma unroll
  for (int tt = 0; tt < 4; ++tt) { acc[tt][0] = {0.f,0.f,0.f,0.f}; acc[tt][1] = {0.f,0.f,0.f,0.f}; }
  #pragma unroll
  for (int c = 0; c < 4; ++c) {
    f16x8 A[4];
    #pragma unroll
    for (int tt = 0; tt < 4; ++tt) {
      const f32x4* eb = (const f32x4*)(ea + (e0 + tt * 16 + m16) * EDIM + g4 * 8 + c * 32);
      f32x4 va = __builtin_nontemporal_load(eb);
      f32x4 vb = __builtin_nontemporal_load(eb + 1);
      A[tt] = cvt8v(va, vb);
    }
    f16x8 b0  = *(const f16x8*)(W1f + ((c * 2 + 0) * 64 + l) * 8);
    f16x8 b1v = *(const f16x8*)(W1f + ((c * 2 + 1) * 64 + l) * 8);
    #pragma unroll
    for (int tt = 0; tt < 4; ++tt) {
      acc[tt][0] = __builtin_amdgcn_mfma_f32_16x16x32_f16(A[tt], b0,  acc[tt][0], 0, 0, 0);
      acc[tt][1] = __builtin_amdgcn_mfma_f32_16x16x32_f16(A[tt], b1v, acc[tt][1], 0, 0, 0);
    }
  }
  float bb0 = b1[m16], bb1 = b1[m16 + 16];
  #pragma unroll
  for (int tt = 0; tt < 4; ++tt) {
    float h00 = fmaxf(acc[tt][0][0] + bb0, 0.f), h01 = fmaxf(acc[tt][0][1] + bb0, 0.f);
    float h02 = fmaxf(acc[tt][0][2] + bb0, 0.f), h03 = fmaxf(acc[tt][0][3] + bb0, 0.f);
    float h10 = fmaxf(acc[tt][1][0] + bb1, 0.f), h11 = fmaxf(acc[tt][1][1] + bb1, 0.f);
    float h12 = fmaxf(acc[tt][1][2] + bb1, 0.f), h13 = fmaxf(acc[tt][1][3] + bb1, 0.f);
    f16x2 d0 = pkrtz(h00, h01), d1 = pkrtz(h02, h03);
    f16x2 d2 = pkrtz(h10, h11), d3 = pkrtz(h12, h13);
    f32x4 w;
    __builtin_memcpy((char*)&w,      &d0, 4);
    __builtin_memcpy((char*)&w + 4,  &d1, 4);
    __builtin_memcpy((char*)&w + 8,  &d2, 4);
    __builtin_memcpy((char*)&w + 12, &d3, 4);
    *(f32x4*)(h1p + e0 * 64 + tt * 1024 + l * 16) = w;   // coalesced 1KB/instr
  }
}

// ---------------- gemm2: c2-sliced messages + scatter (Wf slice is L1-resident) ----------------
// grid = 3 x 2500, slice-major: blocks [s*2500, (s+1)*2500) handle c2 in [s*11, s*11+11)
__global__ __launch_bounds__(256) void gemm2_kernel(
    const float* __restrict__ x, const int* __restrict__ ei,
    const f16* __restrict__ Wf, const char* __restrict__ h1p,
    float* __restrict__ agg)
{
  __shared__ float h1s[4][64][36];
  int t = threadIdx.x;
  int wave = t >> 6, l = t & 63;
  int slice = blockIdx.x / 2500;
  int bidx  = blockIdx.x - slice * 2500;
  int c2lo  = slice * 11;
  long e0 = ((long)bidx * 4 + wave) * 64;
  const int* colp = ei + E_EDGES;
  int m16 = l & 15, g4 = l >> 4;

  // x gather (L2/L3-resident)
  f16x8 nv[4];
  #pragma unroll
  for (int tt = 0; tt < 4; ++tt) {
    int c = colp[e0 + tt * 16 + m16];
    const float* xr = x + (long)c * HID + g4 * 8;
    nv[tt] = cvt8(*(const float4*)xr, *(const float4*)(xr + 4));
  }

  // load h1 fragments (coalesced), unpack into h1s (same indices as fused version)
  #pragma unroll
  for (int tt = 0; tt < 4; ++tt) {
    f32x4 wv = *(const f32x4*)(h1p + e0 * 64 + tt * 1024 + l * 16);
    f16x8 w;
    __builtin_memcpy(&w, &wv, 16);
    #pragma unroll
    for (int r = 0; r < 4; ++r) {
      h1s[wave][tt * 16 + g4 * 4 + r][m16]      = (float)w[r];
      h1s[wave][tt * 16 + g4 * 4 + r][m16 + 16] = (float)w[4 + r];
    }
  }
  if (m16 == 0) {
    #pragma unroll
    for (int tt = 0; tt < 4; ++tt)
      #pragma unroll
      for (int r = 0; r < 4; ++r) h1s[wave][tt * 16 + g4 * 4 + r][32] = 1.f;
  }
  asm volatile("s_waitcnt lgkmcnt(0)" ::: "memory");   // LDS wave-private

  // messages partial: c2 in [c2lo, c2lo+11)
  f32x4 mc[4][2];
  #pragma unroll
  for (int tt = 0; tt < 4; ++tt) { mc[tt][0] = {0.f,0.f,0.f,0.f}; mc[tt][1] = {0.f,0.f,0.f,0.f}; }

  #pragma unroll
  for (int k = 0; k < 11; ++k) {
    int c2 = c2lo + k;
    f16x8 B0 = *(const f16x8*)(Wf + ((c2 * 2 + 0) * 64 + l) * 8);
    f16x8 B1 = *(const f16x8*)(Wf + ((c2 * 2 + 1) * 64 + l) * 8);
    #pragma unroll
    for (int tt = 0; tt < 4; ++tt) {
      float hf = h1s[wave][tt * 16 + m16][c2];
      f16x8 A = nv[tt] * splat8(hf);
      mc[tt][0] = __builtin_amdgcn_mfma_f32_16x16x32_f16(A, B0, mc[tt][0], 0, 0, 0);
      mc[tt][1] = __builtin_amdgcn_mfma_f32_16x16x32_f16(A, B1, mc[tt][1], 0, 0, 0);
    }
  }

  // scatter-add partial sums
  const int* rowp = ei;
  #pragma unroll
  for (int tt = 0; tt < 4; ++tt) {
    #pragma unroll
    for (int r = 0; r < 4; ++r) {
      int er = rowp[e0 + tt * 16 + g4 * 4 + r];
      atomicAdd(&agg[er * HID + m16],      mc[tt][0][r]);
      atomicAdd(&agg[er * HID + m16 + 16], mc[tt][1][r]);
    }
  }
}

// ---------------- MXs[n][o:32][4]: (xz[o]+bz, xr[o]+br, xh[o]+b_in_h, 0) ----------------
__global__ __launch_bounds__(256) void mxp_kernel(
    const float* __restrict__ agg, const float* __restrict__ gk,
    const float* __restrict__ gb, float* __restrict__ MXs)
{
  int tid = blockIdx.x * 256 + threadIdx.x;
  if (tid >= NN * 128) return;
  int n = tid >> 7, rr = tid & 127, o = rr >> 2, q = rr & 3;
  float v = 0.f;
  if (q < 3) {
    int col = q * 32 + o;
    float s = gb[col];
    if (q < 2) s += gb[96 + col];
    const float* ar = agg + n * HID;
    #pragma unroll
    for (int j = 0; j < 32; ++j) s = fmaf(ar[j], gk[j * 96 + col], s);
    v = s;
  }
  MXs[tid] = v;
}

// ---------------- parallel chunked GRU scan with warmup ----------------
__global__ __launch_bounds__(64) void gru_scan(
    const float* __restrict__ MXs, const float* __restrict__ grk,
    const float* __restrict__ gb, const float* __restrict__ hs,
    float* __restrict__ out)
{
  __shared__ float lds[2 * CH * 128 + 256];
  int b = blockIdx.x;
  int start = b * CCH;
  int wstart = start - WARM; if (wstart < 0) wstart = 0;
  int nchunks = (start + CCH - wstart) / CH;
  int warmch = (start - wstart) / CH;

  int l = threadIdx.x;
  int o = l & 31;

  f16x2 Wz[16], Wr[16], Wh[16];
  #pragma unroll
  for (int j = 0; j < 16; ++j) {
    Wz[j] = pkrtz(grk[(2*j)*96 +  0 + o], grk[(2*j+1)*96 +  0 + o]);
    Wr[j] = pkrtz(grk[(2*j)*96 + 32 + o], grk[(2*j+1)*96 + 32 + o]);
    Wh[j] = pkrtz(grk[(2*j)*96 + 64 + o], grk[(2*j+1)*96 + 64 + o]);
  }
  float brh = gb[96 + 64 + o];
  float hcur = (wstart == 0) ? hs[o] : 0.f;

  const char* src = (const char*)(MXs + (size_t)wstart * 128);
  #pragma unroll
  for (int i = 0; i < 25; ++i)
    __builtin_amdgcn_global_load_lds(
        (const __attribute__((address_space(1))) void*)(src + i * 1024 + l * 16),
        (__attribute__((address_space(3))) void*)((char*)lds + i * 1024), 16, 0, 0);

  float* outp = out + (size_t)wstart * HID + o;

  for (int ck = 0; ck < nchunks; ++ck) {
    asm volatile("s_waitcnt vmcnt(0)" ::: "memory");
    if (ck + 1 < nchunks) {
      const char* s2 = src + (size_t)(ck + 1) * CH * 512;
      char* dbuf = (char*)lds + ((ck + 1) & 1) * CH * 512;
      #pragma unroll
      for (int i = 0; i < 25; ++i)
        __builtin_amdgcn_global_load_lds(
            (const __attribute__((address_space(1))) void*)(s2 + i * 1024 + l * 16),
            (__attribute__((address_space(3))) void*)(dbuf + i * 1024), 16, 0, 0);
    }
    const float* buf = lds + (ck & 1) * CH * 128;
    bool wr = (ck >= warmch);

    float4 mx   = *(const float4*)(buf + o * 4);
    float4 mx_n = *(const float4*)(buf + 128 + o * 4);

    #pragma unroll 2
    for (int s = 0; s < CH; ++s) {
      float4 mx_nn = *(const float4*)(buf + (s + 2) * 128 + o * 4);

      int hb = __float_as_int(hcur);
      int nb = __builtin_amdgcn_update_dpp(hb, hb, 0xB1, 0xF, 0xF, true);
      f16x2 pk = pkrtz(__int_as_float(nb), hcur);
      int pki;
      __builtin_memcpy(&pki, &pk, 4);

      float za0 = mx.x, za1 = 0.f, za2 = 0.f, za3 = 0.f;
      float ra0 = mx.y, ra1 = 0.f, ra2 = 0.f, ra3 = 0.f;
      float ha0 = brh,  ha1 = 0.f, ha2 = 0.f, ha3 = 0.f;
      #pragma unroll
      for (int j = 0; j < 16; j += 4) {
        int s0 = __builtin_amdgcn_readlane(pki, 2*j + 1);
        int s1 = __builtin_amdgcn_readlane(pki, 2*j + 3);
        int s2 = __builtin_amdgcn_readlane(pki, 2*j + 5);
        int s3 = __builtin_amdgcn_readlane(pki, 2*j + 7);
        f16x2 p0, p1, p2, p3;
        __builtin_memcpy(&p0, &s0, 4); __builtin_memcpy(&p1, &s1, 4);
        __builtin_memcpy(&p2, &s2, 4); __builtin_memcpy(&p3, &s3, 4);
        za0 = __builtin_amdgcn_fdot2(p0, Wz[j],   za0, false);
        za1 = __builtin_amdgcn_fdot2(p1, Wz[j+1], za1, false);
        za2 = __builtin_amdgcn_fdot2(p2, Wz[j+2], za2, false);
        za3 = __builtin_amdgcn_fdot2(p3, Wz[j+3], za3, false);
        ra0 = __builtin_amdgcn_fdot2(p0, Wr[j],   ra0, false);
        ra1 = __builtin_amdgcn_fdot2(p1, Wr[j+1], ra1, false);
        ra2 = __builtin_amdgcn_fdot2(p2, Wr[j+2], ra2, false);
        ra3 = __builtin_amdgcn_fdot2(p3, Wr[j+3], ra3, false);
        ha0 = __builtin_amdgcn_fdot2(p0, Wh[j],   ha0, false);
        ha1 = __builtin_amdgcn_fdot2(p1, Wh[j+1], ha1, false);
        ha2 = __builtin_amdgcn_fdot2(p2, Wh[j+2], ha2, false);
        ha3 = __builtin_amdgcn_fdot2(p3, Wh[j+3], ha3, false);
      }
      float tz = (za0 + za1) + (za2 + za3);
      float tr = (ra0 + ra1) + (ra2 + ra3);
      float yh = (ha0 + ha1) + (ha2 + ha3);

      float z = __builtin_amdgcn_rcpf(1.f + __builtin_amdgcn_exp2f(-1.442695041f * tz));
      float r = __builtin_amdgcn_rcpf(1.f + __builtin_amdgcn_exp2f(-1.442695041f * tr));

      float pre = fmaf(r, yh, mx.z);
      float e2 = __builtin_amdgcn_exp2f(pre * 2.885390082f);
      float th = fmaf(-2.f, __builtin_amdgcn_rcpf(e2 + 1.f), 1.f);

      float hn = fmaf(z, hcur - th, th);
      if (wr) outp[s * HID] = hn;
      hcur = hn;
      mx = mx_n; mx_n = mx_nn;
    }
    outp += CH * HID;
  }
  if (b == NBLK - 1) out[NN * HID + o] = hcur;
}

extern "C" void kernel_launch(void* const* d_in, const int* in_sizes, int n_in,
                              void* d_out, int out_size, void* d_ws, size_t ws_size,
                              hipStream_t stream) {
  const float* x   = (const float*)d_in[0];
  const int*   ei  = (const int*)d_in[1];
  const float* ea  = (const float*)d_in[2];
  const float* hs  = (const float*)d_in[3];
  const float* w1  = (const float*)d_in[4];
  const float* b1  = (const float*)d_in[5];
  const float* w2  = (const float*)d_in[6];
  const float* b2  = (const float*)d_in[7];
  const float* gk  = (const float*)d_in[8];
  const float* grk = (const float*)d_in[9];
  const float* gb  = (const float*)d_in[10];
  float* out = (float*)d_out;

  char* ws = (char*)d_ws;
  float* agg = (float*)ws;                          // 1.28 MB
  float* MXs = (float*)(ws + 1280000);              // 5.12 MB
  f16*   Wf  = (f16*)(ws + 6400000);                // 67,584 B
  f16*   W1f = (f16*)(ws + 6467584);                // 8,192 B
  char*  h1p = ws + 6475776;                        // 40.96 MB (E x 32 f16, fragment layout)

  prep_kernel<<<dim3(1250), dim3(256), 0, stream>>>(w1, w2, b2, agg, Wf, W1f);
  gemm1_kernel<<<dim3(E_EDGES / 256), dim3(256), 0, stream>>>(ea, b1, W1f, h1p);
  gemm2_kernel<<<dim3(3 * (E_EDGES / 256)), dim3(256), 0, stream>>>(x, ei, Wf, h1p, agg);
  mxp_kernel<<<dim3((NN * 128 + 255) / 256), dim3(256), 0, stream>>>(agg, gk, gb, MXs);
  gru_scan<<<dim3(NBLK), dim3(64), 0, stream>>>(MXs, grk, gb, hs, out);
}

// Round 18
// 225.924 us; speedup vs baseline: 1.5300x; 1.5300x over previous
//
#include <hip/hip_runtime.h>

#define E_EDGES 640000
#define NN 10000
#define HID 32
#define EDIM 128
#define CH 50      // GRU steps per LDS chunk
#define CCH 50     // output steps per scan block
#define WARM 100   // warmup steps (multiple of CH)
#define NBLK 200   // NN / CCH

typedef _Float16 f16;
typedef _Float16 f16x8 __attribute__((ext_vector_type(8)));
typedef _Float16 f16x2 __attribute__((ext_vector_type(2)));
typedef float f32x4 __attribute__((ext_vector_type(4)));

static __device__ __forceinline__ f16x2 pkrtz(float a, float b) {
  auto t = __builtin_amdgcn_cvt_pkrtz(a, b);
  f16x2 r;
  __builtin_memcpy(&r, &t, 4);
  return r;
}

static __device__ __forceinline__ f16x8 cvt8v(f32x4 a, f32x4 b) {
  auto p0 = __builtin_amdgcn_cvt_pkrtz(a[0], a[1]);
  auto p1 = __builtin_amdgcn_cvt_pkrtz(a[2], a[3]);
  auto p2 = __builtin_amdgcn_cvt_pkrtz(b[0], b[1]);
  auto p3 = __builtin_amdgcn_cvt_pkrtz(b[2], b[3]);
  f16x8 r;
  __builtin_memcpy((char*)&r,      &p0, 4);
  __builtin_memcpy((char*)&r + 4,  &p1, 4);
  __builtin_memcpy((char*)&r + 8,  &p2, 4);
  __builtin_memcpy((char*)&r + 12, &p3, 4);
  return r;
}

static __device__ __forceinline__ f16x8 splat8(float h) {
  auto p = __builtin_amdgcn_cvt_pkrtz(h, h);
  int si;
  __builtin_memcpy(&si, &p, 4);
  int v[4] = {si, si, si, si};
  f16x8 r;
  __builtin_memcpy(&r, v, 16);
  return r;
}

// ---------------- prep: zero agg, build f16 fragment-ordered weights ----------------
__global__ __launch_bounds__(256) void prep_kernel(
    const float* __restrict__ w1, const float* __restrict__ w2,
    const float* __restrict__ b2, float* __restrict__ agg,
    f16* __restrict__ Wf, f16* __restrict__ W1f)
{
  int tid = blockIdx.x * 256 + threadIdx.x;
  if (tid < NN * HID) agg[tid] = 0.f;
  if (tid < 33 * 1024) {
    int r = tid & 7, l = (tid >> 3) & 63, h = (tid >> 9) & 1, c2 = tid >> 10;
    int i = (l & 15) + 16 * h, j = (l >> 4) * 8 + r;
    float v = (c2 < 32) ? w2[c2 * 1024 + i * 32 + j] : b2[i * 32 + j];
    Wf[tid] = (f16)v;
  }
  if (tid < 4 * 1024) {
    int r = tid & 7, l = (tid >> 3) & 63, h = (tid >> 9) & 1, c = tid >> 10;
    int d = c * 32 + (l >> 4) * 8 + r, k = (l & 15) + 16 * h;
    W1f[tid] = (f16)w1[d * 32 + k];
  }
}

// ---------------- edges: persistent 4-tile pipeline, 32 edges/wave/tile ----------------
// Per tile: GEMM1 (regs->MFMA) -> h1 LDS -> ISSUE next tile's loads -> GEMM2 -> atomics.
// ea(t+1) HBM latency hides under GEMM2(t)'s Wf/MFMA work.

#define ISSUE(RN, XN, TN)                                                      \
  {                                                                            \
    long e0n = base + (long)(TN) * 128 + wave * 32;                            \
    _Pragma("unroll")                                                          \
    for (int tt = 0; tt < 2; ++tt) {                                           \
      int cc = colp[e0n + tt * 16 + m16];                                      \
      const f32x4* xr = (const f32x4*)(x + (long)cc * HID + g4 * 8);           \
      XN[tt * 2 + 0] = xr[0];                                                  \
      XN[tt * 2 + 1] = xr[1];                                                  \
    }                                                                          \
    _Pragma("unroll")                                                          \
    for (int c = 0; c < 4; ++c)                                                \
      _Pragma("unroll")                                                        \
      for (int tt = 0; tt < 2; ++tt) {                                         \
        const f32x4* eb = (const f32x4*)(ea + (e0n + tt * 16 + m16) * EDIM     \
                                          + g4 * 8 + c * 32);                  \
        RN[c * 4 + tt * 2 + 0] = __builtin_nontemporal_load(eb);               \
        RN[c * 4 + tt * 2 + 1] = __builtin_nontemporal_load(eb + 1);           \
      }                                                                        \
  }

#define TILE(RC, XC, T, PF, RN, XN)                                            \
  {                                                                            \
    long e0 = base + (long)(T) * 128 + wave * 32;                              \
    f32x4 a00 = {0,0,0,0}, a01 = {0,0,0,0}, a10 = {0,0,0,0}, a11 = {0,0,0,0};  \
    _Pragma("unroll")                                                          \
    for (int c = 0; c < 4; ++c) {                                              \
      f16x8 A0 = cvt8v(RC[c * 4 + 0], RC[c * 4 + 1]);                          \
      f16x8 A1 = cvt8v(RC[c * 4 + 2], RC[c * 4 + 3]);                          \
      f16x8 b0  = *(const f16x8*)(W1f + ((c * 2 + 0) * 64 + l) * 8);           \
      f16x8 b1v = *(const f16x8*)(W1f + ((c * 2 + 1) * 64 + l) * 8);           \
      a00 = __builtin_amdgcn_mfma_f32_16x16x32_f16(A0, b0,  a00, 0, 0, 0);     \
      a01 = __builtin_amdgcn_mfma_f32_16x16x32_f16(A0, b1v, a01, 0, 0, 0);     \
      a10 = __builtin_amdgcn_mfma_f32_16x16x32_f16(A1, b0,  a10, 0, 0, 0);     \
      a11 = __builtin_amdgcn_mfma_f32_16x16x32_f16(A1, b1v, a11, 0, 0, 0);     \
    }                                                                          \
    asm volatile("s_waitcnt lgkmcnt(0)" ::: "memory"); /* GEMM2(T-1) h reads done */ \
    _Pragma("unroll")                                                          \
    for (int r = 0; r < 4; ++r) {                                              \
      h1w[(g4 * 4 + r) * 36 + m16]           = fmaxf(a00[r] + bb0, 0.f);       \
      h1w[(g4 * 4 + r) * 36 + m16 + 16]      = fmaxf(a01[r] + bb1, 0.f);       \
      h1w[(16 + g4 * 4 + r) * 36 + m16]      = fmaxf(a10[r] + bb0, 0.f);       \
      h1w[(16 + g4 * 4 + r) * 36 + m16 + 16] = fmaxf(a11[r] + bb1, 0.f);       \
    }                                                                          \
    asm volatile("s_waitcnt lgkmcnt(0)" ::: "memory");                         \
    if (PF) ISSUE(RN, XN, (T) + 1)                                             \
    f16x8 nv0 = cvt8v(XC[0], XC[1]);                                           \
    f16x8 nv1 = cvt8v(XC[2], XC[3]);                                           \
    f32x4 m00 = {0,0,0,0}, m01 = {0,0,0,0}, m10 = {0,0,0,0}, m11 = {0,0,0,0};  \
    _Pragma("unroll")                                                          \
    for (int cb = 0; cb < 8; ++cb) {                                           \
      float4 hv0 = *(const float4*)(h1w + m16 * 36 + cb * 4);                  \
      float4 hv1 = *(const float4*)(h1w + (16 + m16) * 36 + cb * 4);           \
      _Pragma("unroll")                                                        \
      for (int q = 0; q < 4; ++q) {                                            \
        int c2 = cb * 4 + q;                                                   \
        f16x8 B0 = *(const f16x8*)(Wf + ((c2 * 2 + 0) * 64 + l) * 8);          \
        f16x8 B1 = *(const f16x8*)(Wf + ((c2 * 2 + 1) * 64 + l) * 8);          \
        float hf0 = (q == 0) ? hv0.x : (q == 1) ? hv0.y : (q == 2) ? hv0.z : hv0.w; \
        float hf1 = (q == 0) ? hv1.x : (q == 1) ? hv1.y : (q == 2) ? hv1.z : hv1.w; \
        f16x8 A0 = nv0 * splat8(hf0);                                          \
        f16x8 A1 = nv1 * splat8(hf1);                                          \
        m00 = __builtin_amdgcn_mfma_f32_16x16x32_f16(A0, B0, m00, 0, 0, 0);    \
        m01 = __builtin_amdgcn_mfma_f32_16x16x32_f16(A0, B1, m01, 0, 0, 0);    \
        m10 = __builtin_amdgcn_mfma_f32_16x16x32_f16(A1, B0, m10, 0, 0, 0);    \
        m11 = __builtin_amdgcn_mfma_f32_16x16x32_f16(A1, B1, m11, 0, 0, 0);    \
      }                                                                        \
    }                                                                          \
    {                                                                          \
      f16x8 B0 = *(const f16x8*)(Wf + ((32 * 2 + 0) * 64 + l) * 8);            \
      f16x8 B1 = *(const f16x8*)(Wf + ((32 * 2 + 1) * 64 + l) * 8);            \
      m00 = __builtin_amdgcn_mfma_f32_16x16x32_f16(nv0, B0, m00, 0, 0, 0);     \
      m01 = __builtin_amdgcn_mfma_f32_16x16x32_f16(nv0, B1, m01, 0, 0, 0);     \
      m10 = __builtin_amdgcn_mfma_f32_16x16x32_f16(nv1, B0, m10, 0, 0, 0);     \
      m11 = __builtin_amdgcn_mfma_f32_16x16x32_f16(nv1, B1, m11, 0, 0, 0);     \
    }                                                                          \
    _Pragma("unroll")                                                          \
    for (int r = 0; r < 4; ++r) {                                              \
      int er0 = rowp[e0 + g4 * 4 + r];                                         \
      int er1 = rowp[e0 + 16 + g4 * 4 + r];                                    \
      atomicAdd(&agg[er0 * HID + m16],      m00[r]);                           \
      atomicAdd(&agg[er0 * HID + m16 + 16], m01[r]);                           \
      atomicAdd(&agg[er1 * HID + m16],      m10[r]);                           \
      atomicAdd(&agg[er1 * HID + m16 + 16], m11[r]);                           \
    }                                                                          \
  }

__global__ __launch_bounds__(256) void edges_kernel(
    const float* __restrict__ x, const int* __restrict__ ei,
    const float* __restrict__ ea, const float* __restrict__ b1,
    const f16* __restrict__ Wf, const f16* __restrict__ W1f,
    float* __restrict__ agg)
{
  __shared__ float h1s[4][32][36];
  int t = threadIdx.x;
  int wave = t >> 6, l = t & 63;
  const int* colp = ei + E_EDGES;
  const int* rowp = ei;
  int m16 = l & 15, g4 = l >> 4;
  long base = (long)blockIdx.x * 512;     // 4 tiles x 128 edges
  float* h1w = &h1s[wave][0][0];
  float bb0 = b1[m16], bb1 = b1[m16 + 16];

  // ones-column (col 32) written once; GEMM2's c2=32 uses A=nv directly, but keep
  // the column valid anyway for layout consistency.
  if (m16 == 0) {
    #pragma unroll
    for (int r = 0; r < 4; ++r) {
      h1w[(g4 * 4 + r) * 36 + 32] = 1.f;
      h1w[(16 + g4 * 4 + r) * 36 + 32] = 1.f;
    }
  }

  f32x4 RA[16], RB[16];
  f32x4 XA[4], XB[4];

  ISSUE(RA, XA, 0)
  TILE(RA, XA, 0, 1, RB, XB)
  TILE(RB, XB, 1, 1, RA, XA)
  TILE(RA, XA, 2, 1, RB, XB)
  TILE(RB, XB, 3, 0, RA, XA)
}

// ---------------- MXs[n][o:32][4]: (xz[o]+bz, xr[o]+br, xh[o]+b_in_h, 0) ----------------
__global__ __launch_bounds__(256) void mxp_kernel(
    const float* __restrict__ agg, const float* __restrict__ gk,
    const float* __restrict__ gb, float* __restrict__ MXs)
{
  int tid = blockIdx.x * 256 + threadIdx.x;
  if (tid >= NN * 128) return;
  int n = tid >> 7, rr = tid & 127, o = rr >> 2, q = rr & 3;
  float v = 0.f;
  if (q < 3) {
    int col = q * 32 + o;
    float s = gb[col];
    if (q < 2) s += gb[96 + col];
    const float* ar = agg + n * HID;
    #pragma unroll
    for (int j = 0; j < 32; ++j) s = fmaf(ar[j], gk[j * 96 + col], s);
    v = s;
  }
  MXs[tid] = v;
}

// ---------------- parallel chunked GRU scan with warmup ----------------
__global__ __launch_bounds__(64) void gru_scan(
    const float* __restrict__ MXs, const float* __restrict__ grk,
    const float* __restrict__ gb, const float* __restrict__ hs,
    float* __restrict__ out)
{
  __shared__ float lds[2 * CH * 128 + 256];
  int b = blockIdx.x;
  int start = b * CCH;
  int wstart = start - WARM; if (wstart < 0) wstart = 0;
  int nchunks = (start + CCH - wstart) / CH;
  int warmch = (start - wstart) / CH;

  int l = threadIdx.x;
  int o = l & 31;

  f16x2 Wz[16], Wr[16], Wh[16];
  #pragma unroll
  for (int j = 0; j < 16; ++j) {
    Wz[j] = pkrtz(grk[(2*j)*96 +  0 + o], grk[(2*j+1)*96 +  0 + o]);
    Wr[j] = pkrtz(grk[(2*j)*96 + 32 + o], grk[(2*j+1)*96 + 32 + o]);
    Wh[j] = pkrtz(grk[(2*j)*96 + 64 + o], grk[(2*j+1)*96 + 64 + o]);
  }
  float brh = gb[96 + 64 + o];
  float hcur = (wstart == 0) ? hs[o] : 0.f;

  const char* src = (const char*)(MXs + (size_t)wstart * 128);
  #pragma unroll
  for (int i = 0; i < 25; ++i)
    __builtin_amdgcn_global_load_lds(
        (const __attribute__((address_space(1))) void*)(src + i * 1024 + l * 16),
        (__attribute__((address_space(3))) void*)((char*)lds + i * 1024), 16, 0, 0);

  float* outp = out + (size_t)wstart * HID + o;

  for (int ck = 0; ck < nchunks; ++ck) {
    asm volatile("s_waitcnt vmcnt(0)" ::: "memory");
    if (ck + 1 < nchunks) {
      const char* s2 = src + (size_t)(ck + 1) * CH * 512;
      char* dbuf = (char*)lds + ((ck + 1) & 1) * CH * 512;
      #pragma unroll
      for (int i = 0; i < 25; ++i)
        __builtin_amdgcn_global_load_lds(
            (const __attribute__((address_space(1))) void*)(s2 + i * 1024 + l * 16),
            (__attribute__((address_space(3))) void*)(dbuf + i * 1024), 16, 0, 0);
    }
    const float* buf = lds + (ck & 1) * CH * 128;
    bool wr = (ck >= warmch);

    float4 mx   = *(const float4*)(buf + o * 4);
    float4 mx_n = *(const float4*)(buf + 128 + o * 4);

    #pragma unroll 2
    for (int s = 0; s < CH; ++s) {
      float4 mx_nn = *(const float4*)(buf + (s + 2) * 128 + o * 4);

      int hb = __float_as_int(hcur);
      int nb = __builtin_amdgcn_update_dpp(hb, hb, 0xB1, 0xF, 0xF, true);
      f16x2 pk = pkrtz(__int_as_float(nb), hcur);
      int pki;
      __builtin_memcpy(&pki, &pk, 4);

      float za0 = mx.x, za1 = 0.f, za2 = 0.f, za3 = 0.f;
      float ra0 = mx.y, ra1 = 0.f, ra2 = 0.f, ra3 = 0.f;
      float ha0 = brh,  ha1 = 0.f, ha2 = 0.f, ha3 = 0.f;
      #pragma unroll
      for (int j = 0; j < 16; j += 4) {
        int s0 = __builtin_amdgcn_readlane(pki, 2*j + 1);
        int s1 = __builtin_amdgcn_readlane(pki, 2*j + 3);
        int s2 = __builtin_amdgcn_readlane(pki, 2*j + 5);
        int s3 = __builtin_amdgcn_readlane(pki, 2*j + 7);
        f16x2 p0, p1, p2, p3;
        __builtin_memcpy(&p0, &s0, 4); __builtin_memcpy(&p1, &s1, 4);
        __builtin_memcpy(&p2, &s2, 4); __builtin_memcpy(&p3, &s3, 4);
        za0 = __builtin_amdgcn_fdot2(p0, Wz[j],   za0, false);
        za1 = __builtin_amdgcn_fdot2(p1, Wz[j+1], za1, false);
        za2 = __builtin_amdgcn_fdot2(p2, Wz[j+2], za2, false);
        za3 = __builtin_amdgcn_fdot2(p3, Wz[j+3], za3, false);
        ra0 = __builtin_amdgcn_fdot2(p0, Wr[j],   ra0, false);
        ra1 = __builtin_amdgcn_fdot2(p1, Wr[j+1], ra1, false);
        ra2 = __builtin_amdgcn_fdot2(p2, Wr[j+2], ra2, false);
        ra3 = __builtin_amdgcn_fdot2(p3, Wr[j+3], ra3, false);
        ha0 = __builtin_amdgcn_fdot2(p0, Wh[j],   ha0, false);
        ha1 = __builtin_amdgcn_fdot2(p1, Wh[j+1], ha1, false);
        ha2 = __builtin_amdgcn_fdot2(p2, Wh[j+2], ha2, false);
        ha3 = __builtin_amdgcn_fdot2(p3, Wh[j+3], ha3, false);
      }
      float tz = (za0 + za1) + (za2 + za3);
      float tr = (ra0 + ra1) + (ra2 + ra3);
      float yh = (ha0 + ha1) + (ha2 + ha3);

      float z = __builtin_amdgcn_rcpf(1.f + __builtin_amdgcn_exp2f(-1.442695041f * tz));
      float r = __builtin_amdgcn_rcpf(1.f + __builtin_amdgcn_exp2f(-1.442695041f * tr));

      float pre = fmaf(r, yh, mx.z);
      float e2 = __builtin_amdgcn_exp2f(pre * 2.885390082f);
      float th = fmaf(-2.f, __builtin_amdgcn_rcpf(e2 + 1.f), 1.f);

      float hn = fmaf(z, hcur - th, th);
      if (wr) outp[s * HID] = hn;
      hcur = hn;
      mx = mx_n; mx_n = mx_nn;
    }
    outp += CH * HID;
  }
  if (b == NBLK - 1) out[NN * HID + o] = hcur;
}

extern "C" void kernel_launch(void* const* d_in, const int* in_sizes, int n_in,
                              void* d_out, int out_size, void* d_ws, size_t ws_size,
                              hipStream_t stream) {
  const float* x   = (const float*)d_in[0];
  const int*   ei  = (const int*)d_in[1];
  const float* ea  = (const float*)d_in[2];
  const float* hs  = (const float*)d_in[3];
  const float* w1  = (const float*)d_in[4];
  const float* b1  = (const float*)d_in[5];
  const float* w2  = (const float*)d_in[6];
  const float* b2  = (const float*)d_in[7];
  const float* gk  = (const float*)d_in[8];
  const float* grk = (const float*)d_in[9];
  const float* gb  = (const float*)d_in[10];
  float* out = (float*)d_out;

  char* ws = (char*)d_ws;
  float* agg = (float*)ws;                          // 1.28 MB
  float* MXs = (float*)(ws + 1280000);              // 5.12 MB
  f16*   Wf  = (f16*)(ws + 6400000);                // 67,584 B
  f16*   W1f = (f16*)(ws + 6467584);                // 8,192 B

  prep_kernel<<<dim3(1250), dim3(256), 0, stream>>>(w1, w2, b2, agg, Wf, W1f);
  edges_kernel<<<dim3(E_EDGES / 512), dim3(256), 0, stream>>>(x, ei, ea, b1, Wf, W1f, agg);
  mxp_kernel<<<dim3((NN * 128 + 255) / 256), dim3(256), 0, stream>>>(agg, gk, gb, MXs);
  gru_scan<<<dim3(NBLK), dim3(64), 0, stream>>>(MXs, grk, gb, hs, out);
}